// Round 8
// baseline (59.009 us; speedup 1.0000x reference)
//
#include <hip/hip_runtime.h>

// Deformable depthwise conv1d (fp32), MI355X.
// Round 8: in-register bilinear sampling. offs ~ N(0,0.13) for this problem,
// so floor(offs) in {-1,0} almost surely -> the gather targets live in the
// thread's 9-float register window. Replace the data-dependent ds_read2
// (the ~120cy critical-path latency every prior round kept) with 2 cndmasks.
// Rare/adversarial offsets (|offs|>=1) fall back to a wave-uniform re-run of
// the iteration via the proven padded-LDS gather path.

constexpr int B_ = 8;
constexpr int C_ = 512;
constexpr int T_ = 4096;
constexpr int K_ = 7;
constexpr int T_OUT = T_ - K_ + 1;      // 4090
constexpr int BLOCK = 256;
constexpr int P_ = 16;                  // zero pad each side
constexpr int ROWP = P_ + T_ + P_;      // 4128 floats = 16.5 KB
constexpr int SPAN = 2 * BLOCK;         // 512 t per iter
constexpr int NIT = 8;
constexpr int WN = 9;                   // register window x[t-1 .. t+7]

typedef float v2f __attribute__((ext_vector_type(2)));

__device__ __forceinline__ float fract_f(float p) {
#if __has_builtin(__builtin_amdgcn_fractf)
    return __builtin_amdgcn_fractf(p);      // v_fract_f32: p - floor(p)
#else
    return p - floorf(p);
#endif
}

__device__ __forceinline__ float clamp01hi(float a, float hi) {
#if __has_builtin(__builtin_amdgcn_fmed3f)
    return __builtin_amdgcn_fmed3f(a, 0.0f, hi);   // v_med3_f32
#else
    return fminf(fmaxf(a, 0.0f), hi);
#endif
}

__global__ __launch_bounds__(BLOCK)
void deform_dwconv1d_kernel(const float* __restrict__ x,
                            const float* __restrict__ weight,
                            const float* __restrict__ offset_w,
                            const float* __restrict__ offset_b,
                            float* __restrict__ out)
{
    __shared__ float rowp[ROWP];

    const int bc  = blockIdx.x;        // b*C + c
    const int c   = bc & (C_ - 1);
    const int tid = threadIdx.x;

    if (tid < P_) {
        rowp[tid] = 0.0f;
        rowp[P_ + T_ + tid] = 0.0f;
    }

    const float* xrow = x + (size_t)bc * T_;
    const float4* src = reinterpret_cast<const float4*>(xrow);
    float4* dst = reinterpret_cast<float4*>(rowp + P_);
    #pragma unroll
    for (int i = 0; i < T_ / 4 / BLOCK; ++i)
        dst[tid + i * BLOCK] = src[tid + i * BLOCK];

    // per-channel weights: uniform addresses -> scalar loads / SGPRs
    float ow[K_ * K_];
    #pragma unroll
    for (int i = 0; i < K_ * K_; ++i) ow[i] = offset_w[c * K_ * K_ + i];
    float wgt[K_], ob[K_];
    #pragma unroll
    for (int k = 0; k < K_; ++k) {
        wgt[k] = weight[c * K_ + k];
        ob[k]  = offset_b[c * K_ + k];
    }

    __syncthreads();

    float* orow = out + (size_t)bc * T_OUT;
    constexpr float HI = (float)(ROWP - 2);   // 4126: pad zeros beyond

    #pragma unroll
    for (int it = 0; it < NIT; ++it) {
        const int tA = it * SPAN + tid;            // lane-stride-1, max 3839
        const int tB = tA + BLOCK;                 // lane-stride-1, max 4095

        // 9-float windows W[j] = x[t-1+j] from the padded LDS row, stored as
        // {A,B} v2f pairs so the packed conv reads them with no reg moves.
        // Indices: [P_-1+0 .. P_-1+4095+8] = [15..4118] < 4128, always safe.
        v2f W[WN];
        #pragma unroll
        for (int j = 0; j < WN; ++j)
            W[j] = v2f{rowp[P_ - 1 + tA + j], rowp[P_ - 1 + tB + j]};

        float accA = 0.0f, accB = 0.0f;
        float badm = 0.0f;                 // max |offs| over taps & outputs
        float offsA[K_], offsB[K_];        // kept for rare fallback reuse

        #pragma unroll
        for (int k = 0; k < K_; ++k) {
            // packed offset conv: offs = bias + sum_j x[t+j]*ow[k][j]
            v2f o = v2f{ob[k], ob[k]};
            #pragma unroll
            for (int j = 0; j < K_; ++j) {
                const float m = ow[k * K_ + j];
                o = __builtin_elementwise_fma(W[j + 1], v2f{m, m}, o);
            }
            offsA[k] = o.x;
            offsB[k] = o.y;
            badm = fmaxf(badm, fmaxf(fabsf(o.x), fabsf(o.y)));

            // in-register bilinear: offs in [-1,1) => i0 = t+k-1 (offs<0)
            // or t+k (offs>=0); u = fract(offs) in both cases.
            const bool sA = (o.x >= 0.0f);
            const bool sB = (o.y >= 0.0f);
            const float g0A = sA ? W[k + 1].x : W[k].x;
            const float g1A = sA ? W[k + 2].x : W[k + 1].x;
            const float g0B = sB ? W[k + 1].y : W[k].y;
            const float g1B = sB ? W[k + 2].y : W[k + 1].y;
            const float uA = fract_f(o.x);
            const float uB = fract_f(o.y);

            accA = fmaf(fmaf(uA, g1A - g0A, g0A), wgt[k], accA);
            accB = fmaf(fmaf(uB, g1B - g0B, g0B), wgt[k], accB);
        }

        // rare exact fallback: any |offs| >= 1 -> redo both outputs via the
        // padded-LDS gather path (wave-uniform branch, ~never taken).
        if (__any(badm >= 1.0f)) {
            accA = 0.0f; accB = 0.0f;
            const float tfA = (float)(tA + P_);
            const float tfB = (float)(tB + P_);
            #pragma unroll
            for (int k = 0; k < K_; ++k) {
                const float pA = clamp01hi(offsA[k] + tfA + (float)k, HI);
                const float pB = clamp01hi(offsB[k] + tfB + (float)k, HI);
                const int   iA = (int)pA;
                const int   iB = (int)pB;
                const float uA = fract_f(pA);
                const float uB = fract_f(pB);
                const float g0A = rowp[iA], g1A = rowp[iA + 1];
                const float g0B = rowp[iB], g1B = rowp[iB + 1];
                accA = fmaf(fmaf(uA, g1A - g0A, g0A), wgt[k], accA);
                accB = fmaf(fmaf(uB, g1B - g0B, g0B), wgt[k], accB);
            }
        }

        orow[tA] = accA;                            // tA <= 3839 always valid
        if (it < NIT - 1 || tid < T_OUT - (NIT - 1) * SPAN - BLOCK)  // tB < 4090
            orow[tB] = accB;
    }
}

extern "C" void kernel_launch(void* const* d_in, const int* in_sizes, int n_in,
                              void* d_out, int out_size, void* d_ws, size_t ws_size,
                              hipStream_t stream) {
    const float* x        = (const float*)d_in[0];
    const float* weight   = (const float*)d_in[1];
    const float* offset_w = (const float*)d_in[2];
    const float* offset_b = (const float*)d_in[3];
    float* out = (float*)d_out;

    deform_dwconv1d_kernel<<<B_ * C_, BLOCK, 0, stream>>>(
        x, weight, offset_w, offset_b, out);
}

// Round 9
// 56.853 us; speedup vs baseline: 1.0379x; 1.0379x over previous
//
#include <hip/hip_runtime.h>

// Deformable depthwise conv1d (fp32), MI355X.
// Round 9: coefficient-form in-register bilinear. For |offs|<=1 the sample is
// a 3-tap stencil with branchless weights a=max(-o,0), b=1-|o|, c=max(o,0).
// Accumulate per-position coefficients C[m] += w_k*{a,b,c}, then one 9-term
// dot with the register window. Deletes all cmp/cndmask/fract/blend ops of
// R8 (~40% of the tap loop). Fully v2f-packed across the strided output pair.
// Exact wave-uniform fallback via padded-LDS gathers if any |offs|>1.

constexpr int B_ = 8;
constexpr int C_ = 512;
constexpr int T_ = 4096;
constexpr int K_ = 7;
constexpr int T_OUT = T_ - K_ + 1;      // 4090
constexpr int BLOCK = 256;
constexpr int P_ = 16;                  // zero pad each side
constexpr int ROWP = P_ + T_ + P_;      // 4128 floats = 16.5 KB
constexpr int SPAN = 2 * BLOCK;         // 512 t per iter
constexpr int NIT = 8;
constexpr int WN = 9;                   // register window x[t-1 .. t+7]

typedef float v2f __attribute__((ext_vector_type(2)));

__device__ __forceinline__ float fract_f(float p) {
#if __has_builtin(__builtin_amdgcn_fractf)
    return __builtin_amdgcn_fractf(p);      // v_fract_f32: p - floor(p)
#else
    return p - floorf(p);
#endif
}

__device__ __forceinline__ float clamp01hi(float a, float hi) {
#if __has_builtin(__builtin_amdgcn_fmed3f)
    return __builtin_amdgcn_fmed3f(a, 0.0f, hi);   // v_med3_f32
#else
    return fminf(fmaxf(a, 0.0f), hi);
#endif
}

__global__ __launch_bounds__(BLOCK)
void deform_dwconv1d_kernel(const float* __restrict__ x,
                            const float* __restrict__ weight,
                            const float* __restrict__ offset_w,
                            const float* __restrict__ offset_b,
                            float* __restrict__ out)
{
    __shared__ float rowp[ROWP];

    const int bc  = blockIdx.x;        // b*C + c
    const int c   = bc & (C_ - 1);
    const int tid = threadIdx.x;

    if (tid < P_) {
        rowp[tid] = 0.0f;
        rowp[P_ + T_ + tid] = 0.0f;
    }

    const float* xrow = x + (size_t)bc * T_;
    const float4* src = reinterpret_cast<const float4*>(xrow);
    float4* dst = reinterpret_cast<float4*>(rowp + P_);
    #pragma unroll
    for (int i = 0; i < T_ / 4 / BLOCK; ++i)
        dst[tid + i * BLOCK] = src[tid + i * BLOCK];

    // per-channel weights: uniform addresses -> scalar loads / SGPRs
    float ow[K_ * K_];
    #pragma unroll
    for (int i = 0; i < K_ * K_; ++i) ow[i] = offset_w[c * K_ * K_ + i];
    float wgt[K_], ob[K_];
    #pragma unroll
    for (int k = 0; k < K_; ++k) {
        wgt[k] = weight[c * K_ + k];
        ob[k]  = offset_b[c * K_ + k];
    }

    __syncthreads();

    float* orow = out + (size_t)bc * T_OUT;
    constexpr float HI = (float)(ROWP - 2);   // 4126: pad zeros beyond

    #pragma unroll
    for (int it = 0; it < NIT; ++it) {
        const int tA = it * SPAN + tid;            // lane-stride-1, max 3839
        const int tB = tA + BLOCK;                 // lane-stride-1, max 4095

        // 9-value windows W[j] = {x[tA-1+j], x[tB-1+j]} from padded LDS.
        // Indices in [15, 4118] -- always in-bounds. Lane-adjacent stride-1
        // addresses: conflict-free (R8 measured ~0).
        v2f W[WN];
        #pragma unroll
        for (int j = 0; j < WN; ++j)
            W[j] = v2f{rowp[P_ - 1 + tA + j], rowp[P_ - 1 + tB + j]};

        // per-position coefficients
        v2f Cf[WN];
        #pragma unroll
        for (int m = 0; m < WN; ++m) Cf[m] = v2f{0.0f, 0.0f};

        float badm = 0.0f;                 // max |offs| over taps & outputs
        v2f offs[K_];                      // kept for the rare fallback

        #pragma unroll
        for (int k = 0; k < K_; ++k) {
            // packed offset conv: offs = bias + sum_j x[t+j]*ow[k][j]
            v2f o = v2f{ob[k], ob[k]};
            #pragma unroll
            for (int j = 0; j < K_; ++j) {
                const float m = ow[k * K_ + j];
                o = __builtin_elementwise_fma(W[j + 1], v2f{m, m}, o);
            }
            offs[k] = o;
            badm = fmaxf(badm, fmaxf(fabsf(o.x), fabsf(o.y)));  // v_max3+|.|

            // branchless 3-tap stencil weights (exact for |o| <= 1):
            //   a = max(-o,0), b = 1-|o|, c = max(o,0)
            const v2f a = {fmaxf(-o.x, 0.0f), fmaxf(-o.y, 0.0f)};
            const v2f cc = {fmaxf(o.x, 0.0f), fmaxf(o.y, 0.0f)};
            const v2f b = {1.0f - fabsf(o.x), 1.0f - fabsf(o.y)};

            const float wk = wgt[k];
            const v2f wk2 = {wk, wk};
            Cf[k]     = __builtin_elementwise_fma(a,  wk2, Cf[k]);
            Cf[k + 1] = __builtin_elementwise_fma(b,  wk2, Cf[k + 1]);
            Cf[k + 2] = __builtin_elementwise_fma(cc, wk2, Cf[k + 2]);
        }

        // final 9-term dot with the window
        v2f acc = v2f{0.0f, 0.0f};
        #pragma unroll
        for (int m = 0; m < WN; ++m)
            acc = __builtin_elementwise_fma(Cf[m], W[m], acc);

        // rare exact fallback: any |offs| > 1 -> redo via padded-LDS gathers
        // (wave-uniform; never taken for this data distribution).
        if (__any(badm > 1.0f)) {
            float accA = 0.0f, accB = 0.0f;
            const float tfA = (float)(tA + P_);
            const float tfB = (float)(tB + P_);
            #pragma unroll
            for (int k = 0; k < K_; ++k) {
                const float pA = clamp01hi(offs[k].x + tfA + (float)k, HI);
                const float pB = clamp01hi(offs[k].y + tfB + (float)k, HI);
                const int   iA = (int)pA;
                const int   iB = (int)pB;
                const float uA = fract_f(pA);
                const float uB = fract_f(pB);
                const float g0A = rowp[iA], g1A = rowp[iA + 1];
                const float g0B = rowp[iB], g1B = rowp[iB + 1];
                accA = fmaf(fmaf(uA, g1A - g0A, g0A), wgt[k], accA);
                accB = fmaf(fmaf(uB, g1B - g0B, g0B), wgt[k], accB);
            }
            acc = v2f{accA, accB};
        }

        orow[tA] = acc.x;                           // tA <= 3839 always valid
        if (it < NIT - 1 || tid < T_OUT - (NIT - 1) * SPAN - BLOCK)  // tB < 4090
            orow[tB] = acc.y;
    }
}

extern "C" void kernel_launch(void* const* d_in, const int* in_sizes, int n_in,
                              void* d_out, int out_size, void* d_ws, size_t ws_size,
                              hipStream_t stream) {
    const float* x        = (const float*)d_in[0];
    const float* weight   = (const float*)d_in[1];
    const float* offset_w = (const float*)d_in[2];
    const float* offset_b = (const float*)d_in[3];
    float* out = (float*)d_out;

    deform_dwconv1d_kernel<<<B_ * C_, BLOCK, 0, stream>>>(
        x, weight, offset_w, offset_b, out);
}

// Round 10
// 44.912 us; speedup vs baseline: 1.3139x; 1.2659x over previous
//
#include <hip/hip_runtime.h>

// Deformable depthwise conv1d (fp32), MI355X.
// Round 10: scalar-math coefficient form (packed v2f was a mirage: VOP3P
// fp32 needs register pairs; splats/moves cost more than they saved).
//   s_k = x[t+k] + a*(x[t+k-1]-x[t+k]) - c*(x[t+k+1]-x[t+k]),
//   a = max(-o,0), c = max(o,0)      (exact for |o| <= 1)
// Differences E[] shared across taps AND the 4 consecutive outputs/thread.
// Windows via 4x ds_read_b128 from the zero-padded LDS row (16B-aligned,
// conflict-free) -> LDS instrs ~9/output -> 1/output. Exact wave-uniform
// fallback via clamped LDS gathers when any |offs| > 1 (never for this data).

constexpr int B_ = 8;
constexpr int C_ = 512;
constexpr int T_ = 4096;
constexpr int K_ = 7;
constexpr int T_OUT = T_ - K_ + 1;      // 4090
constexpr int BLOCK = 256;
constexpr int P_ = 16;                  // zero pad each side
constexpr int ROWP = P_ + T_ + P_;      // 4128 floats = 16.5 KB
constexpr int NOUT = 4;                 // consecutive outputs per thread
constexpr int SPAN = NOUT * BLOCK;      // 1024 t per iter
constexpr int NIT = 4;

__device__ __forceinline__ float fract_f(float p) {
#if __has_builtin(__builtin_amdgcn_fractf)
    return __builtin_amdgcn_fractf(p);      // v_fract_f32: p - floor(p)
#else
    return p - floorf(p);
#endif
}

__device__ __forceinline__ float clamp01hi(float a, float hi) {
#if __has_builtin(__builtin_amdgcn_fmed3f)
    return __builtin_amdgcn_fmed3f(a, 0.0f, hi);   // v_med3_f32
#else
    return fminf(fmaxf(a, 0.0f), hi);
#endif
}

__global__ __launch_bounds__(BLOCK)
void deform_dwconv1d_kernel(const float* __restrict__ x,
                            const float* __restrict__ weight,
                            const float* __restrict__ offset_w,
                            const float* __restrict__ offset_b,
                            float* __restrict__ out)
{
    __shared__ float rowp[ROWP];

    const int bc  = blockIdx.x;        // b*C + c
    const int c   = bc & (C_ - 1);
    const int tid = threadIdx.x;

    if (tid < P_) {
        rowp[tid] = 0.0f;
        rowp[P_ + T_ + tid] = 0.0f;
    }

    const float* xrow = x + (size_t)bc * T_;
    const float4* src = reinterpret_cast<const float4*>(xrow);
    float4* dst = reinterpret_cast<float4*>(rowp + P_);
    #pragma unroll
    for (int i = 0; i < T_ / 4 / BLOCK; ++i)
        dst[tid + i * BLOCK] = src[tid + i * BLOCK];

    // per-channel weights: uniform indices -> scalar (SGPR) loads
    float ow[K_ * K_];
    #pragma unroll
    for (int i = 0; i < K_ * K_; ++i) ow[i] = offset_w[c * K_ * K_ + i];
    float wgt[K_], ob[K_];
    #pragma unroll
    for (int k = 0; k < K_; ++k) {
        wgt[k] = weight[c * K_ + k];
        ob[k]  = offset_b[c * K_ + k];
    }

    __syncthreads();

    float* orow = out + (size_t)bc * T_OUT;
    constexpr float HI = (float)(ROWP - 2);   // 4126: pad zeros beyond

    #pragma unroll
    for (int it = 0; it < NIT; ++it) {
        const int t0 = it * SPAN + tid * NOUT;   // multiple of 4, max 4092

        // window x[t0-4 .. t0+11] via 4x ds_read_b128 (byte addr (12+t0)*4,
        // 16B-aligned; lane stride 16B -> <=2-way bank alias = free).
        // Max element index 12+4092+15 = 4119 < 4128: always in-bounds.
        const float4* wp = reinterpret_cast<const float4*>(rowp + (P_ - 4) + t0);
        const float4 F0 = wp[0], F1 = wp[1], F2 = wp[2], F3 = wp[3];
        const float Wf[16] = {F0.x, F0.y, F0.z, F0.w,  F1.x, F1.y, F1.z, F1.w,
                              F2.x, F2.y, F2.z, F2.w,  F3.x, F3.y, F3.z, F3.w};
        // Wf[m] = x[t0-4+m]

        // shared differences: E[m] = Wf[m] - Wf[m+1]
        float E[14];
        #pragma unroll
        for (int m = 3; m < 14; ++m) E[m] = Wf[m] - Wf[m + 1];

        float acc[NOUT];
        float badm = 0.0f;                 // max |offs| over taps & outputs

        #pragma unroll
        for (int r = 0; r < NOUT; ++r) {
            float a2 = 0.0f;
            #pragma unroll
            for (int k = 0; k < K_; ++k) {
                // offset conv: o = bias + sum_j x[t+j]*ow[k][j], t = t0+r
                float o = ob[k];
                #pragma unroll
                for (int j = 0; j < K_; ++j)
                    o = fmaf(Wf[4 + r + j], ow[k * K_ + j], o);

                badm = fmaxf(badm, fabsf(o));

                // branchless 3-tap stencil, exact for |o| <= 1
                const float an = fmaxf(-o, 0.0f);
                const float cn = fmaxf(o, 0.0f);
                float s = fmaf(an, E[3 + r + k], Wf[4 + r + k]);
                s = fmaf(cn, -E[4 + r + k], s);
                a2 = fmaf(wgt[k], s, a2);
            }
            acc[r] = a2;
        }

        // exact fallback (wave-uniform, ~never taken): any |offs| > 1 ->
        // redo all 4 outputs via the clamped padded-LDS gather path.
        if (__any(badm > 1.0f)) {
            #pragma unroll
            for (int r = 0; r < NOUT; ++r) {
                float a2 = 0.0f;
                const float tf = (float)(t0 + r + P_);
                #pragma unroll
                for (int k = 0; k < K_; ++k) {
                    float o = ob[k];
                    #pragma unroll
                    for (int j = 0; j < K_; ++j)
                        o = fmaf(Wf[4 + r + j], ow[k * K_ + j], o);
                    const float p  = clamp01hi(o + tf + (float)k, HI);
                    const int   i0 = (int)p;                 // p>=0: trunc==floor
                    const float u  = fract_f(p);
                    const float g0 = rowp[i0], g1 = rowp[i0 + 1];
                    a2 = fmaf(fmaf(u, g1 - g0, g0), wgt[k], a2);
                }
                acc[r] = a2;
            }
        }

        // stores: two 8B-aligned float2 per thread; guards only in the tail
        if (it < NIT - 1) {
            *reinterpret_cast<float2*>(orow + t0)     = make_float2(acc[0], acc[1]);
            *reinterpret_cast<float2*>(orow + t0 + 2) = make_float2(acc[2], acc[3]);
        } else {
            if (t0 + 1 < T_OUT)
                *reinterpret_cast<float2*>(orow + t0)     = make_float2(acc[0], acc[1]);
            if (t0 + 3 < T_OUT)
                *reinterpret_cast<float2*>(orow + t0 + 2) = make_float2(acc[2], acc[3]);
        }
    }
}

extern "C" void kernel_launch(void* const* d_in, const int* in_sizes, int n_in,
                              void* d_out, int out_size, void* d_ws, size_t ws_size,
                              hipStream_t stream) {
    const float* x        = (const float*)d_in[0];
    const float* weight   = (const float*)d_in[1];
    const float* offset_w = (const float*)d_in[2];
    const float* offset_b = (const float*)d_in[3];
    float* out = (float*)d_out;

    deform_dwconv1d_kernel<<<B_ * C_, BLOCK, 0, stream>>>(
        x, weight, offset_w, offset_b, out);
}